// Round 5
// baseline (335.263 us; speedup 1.0000x reference)
//
#include <hip/hip_runtime.h>

// DCNv4 on gfx950 — bf16 MFMA pipeline, group-planar value layout.
// K0: weights -> bf16 transposed [n][k]
// K2: dwconv3x3 sliding-window row kernel -> xdw bf16 + x_bf16
// K1: value = x @ vp_w + vp_b      (MFMA M=64, writes group-planar bf16)
// K3: fused om GEMM (8 waves x 7 tiles) -> LDS (32-stride) -> sampling
//     (lane remap: 16 consecutive pixels per 16-lane group, fixed g)
// K4: out = sampled @ op_w         (MFMA M=64, fp32 NHWC out)

typedef __bf16 bf16_t;
typedef bf16_t bf16x8 __attribute__((ext_vector_type(8)));
typedef bf16_t bf16x4 __attribute__((ext_vector_type(4)));
typedef float f32x4 __attribute__((ext_vector_type(4)));

namespace {
constexpr int NN = 8, HH = 64, WW = 64, CC = 256;
constexpr int G = 32, GC = 8, OMD = 864;      // G*9*3
constexpr int NPIX = NN * HH * WW;            // 32768
constexpr int OMD_PAD = 896;                  // 56 tiles of 16 (2 dummy)
}

// ---------------- K0: convert + transpose weights to bf16 [n][k] ----------------
__global__ __launch_bounds__(256) void convert_weights_kernel(
    const float* __restrict__ om_w, const float* __restrict__ vp_w,
    const float* __restrict__ op_w, bf16_t* __restrict__ om_wT,
    bf16_t* __restrict__ vp_wT, bf16_t* __restrict__ op_wT) {
  const int t = threadIdx.x;
  const int b = blockIdx.x;
  if (b < OMD_PAD) {
    om_wT[(size_t)b * CC + t] = (b < OMD) ? (bf16_t)om_w[(size_t)t * OMD + b] : (bf16_t)0.0f;
  } else if (b < OMD_PAD + 256) {
    const int n = b - OMD_PAD;
    vp_wT[(size_t)n * CC + t] = (bf16_t)vp_w[(size_t)t * CC + n];
  } else {
    const int n = b - OMD_PAD - 256;
    op_wT[(size_t)n * CC + t] = (bf16_t)op_w[(size_t)t * CC + n];
  }
}

// ---------------- K2: dwconv3x3 sliding-window; block = one image row ----------
__global__ __launch_bounds__(256) void dwconv_row_kernel(
    const float* __restrict__ x, const float* __restrict__ dw_w,
    const float* __restrict__ dw_b, bf16_t* __restrict__ xdw,
    bf16_t* __restrict__ x_bf16) {
  const int t = threadIdx.x;
  const int cq = (t & 63) * 4;   // channel base
  const int seg = t >> 6;        // wave id = x segment (16 px each)
  const int row = blockIdx.x;    // n*64 + y
  const int y = row & 63;
  const bool up = (y > 0), dn = (y < HH - 1);
  const float* xrow = x + (size_t)row * WW * CC + cq;

  const float4 bias = *(const float4*)&dw_b[cq];
  float4 dw[9];
#pragma unroll
  for (int i = 0; i < 9; ++i) dw[i] = *(const float4*)&dw_w[(size_t)i * CC + cq];

  const float4 zero = make_float4(0.f, 0.f, 0.f, 0.f);
  auto loadcol = [&](int xx, float4 c[3]) {
    if (xx < 0 || xx >= WW) { c[0] = c[1] = c[2] = zero; return; }
    c[0] = up ? *(const float4*)(xrow + ((size_t)xx - WW) * CC) : zero;
    c[1] = *(const float4*)(xrow + (size_t)xx * CC);
    c[2] = dn ? *(const float4*)(xrow + ((size_t)xx + WW) * CC) : zero;
  };

  const int x0 = seg * 16;
  float4 cm[3], cc[3], cp[3];
  loadcol(x0 - 1, cm);
  loadcol(x0, cc);

  for (int xx = x0; xx < x0 + 16; ++xx) {
    loadcol(xx + 1, cp);
    float4 a = bias;
#pragma unroll
    for (int r = 0; r < 3; ++r) {
      const float4 w0 = dw[r * 3 + 0], w1 = dw[r * 3 + 1], w2 = dw[r * 3 + 2];
      a.x = fmaf(cm[r].x, w0.x, fmaf(cc[r].x, w1.x, fmaf(cp[r].x, w2.x, a.x)));
      a.y = fmaf(cm[r].y, w0.y, fmaf(cc[r].y, w1.y, fmaf(cp[r].y, w2.y, a.y)));
      a.z = fmaf(cm[r].z, w0.z, fmaf(cc[r].z, w1.z, fmaf(cp[r].z, w2.z, a.z)));
      a.w = fmaf(cm[r].w, w0.w, fmaf(cc[r].w, w1.w, fmaf(cp[r].w, w2.w, a.w)));
    }
    const size_t o = (size_t)(row * WW + xx) * CC + cq;
    bf16x4 av, cv;
    av[0] = (bf16_t)a.x; av[1] = (bf16_t)a.y; av[2] = (bf16_t)a.z; av[3] = (bf16_t)a.w;
    cv[0] = (bf16_t)cc[1].x; cv[1] = (bf16_t)cc[1].y;
    cv[2] = (bf16_t)cc[1].z; cv[3] = (bf16_t)cc[1].w;
    *(bf16x4*)&xdw[o] = av;
    *(bf16x4*)&x_bf16[o] = cv;
#pragma unroll
    for (int r = 0; r < 3; ++r) { cm[r] = cc[r]; cc[r] = cp[r]; }
  }
}

// ---------------- K1/K4: 256->256 GEMM, M=64/block, 8 waves ----------------
// wave: (m-tile = w>>1, n-half = w&1); acc[8] f32x4.
// OUTMODE 0: fp32 NHWC out. OUTMODE 1: bf16 group-planar value out.
template <bool HAS_BIAS, int OUTMODE>
__global__ __launch_bounds__(512, 4) void mfma_gemm256_kernel(
    const bf16_t* __restrict__ A, const bf16_t* __restrict__ BT,
    const float* __restrict__ bias, void* __restrict__ outp) {
  const int lane = threadIdx.x & 63;
  const int wave = threadIdx.x >> 6;
  const int mq = wave >> 1;
  const int nh = wave & 1;
  const int pix0 = blockIdx.x * 64 + mq * 16;
  const int m = lane & 15;
  const int kq = lane >> 4;

  const bf16_t* Ap = A + (size_t)(pix0 + m) * CC + kq * 8;
  const bf16_t* Bp = BT + (size_t)(nh * 128 + m) * CC + kq * 8;

  f32x4 acc[8] = {};
#pragma unroll
  for (int ks = 0; ks < 8; ++ks) {
    const bf16x8 a = *(const bf16x8*)(Ap + ks * 32);
#pragma unroll
    for (int i = 0; i < 8; ++i) {
      const bf16x8 b = *(const bf16x8*)(Bp + (size_t)i * 16 * CC + ks * 32);
      acc[i] = __builtin_amdgcn_mfma_f32_16x16x32_bf16(a, b, acc[i], 0, 0, 0);
    }
  }

  const int row0 = pix0 + kq * 4;
#pragma unroll
  for (int i = 0; i < 8; ++i) {
    const int n = nh * 128 + i * 16 + m;
    const float bs = HAS_BIAS ? bias[n] : 0.0f;
#pragma unroll
    for (int r = 0; r < 4; ++r) {
      const int pix = row0 + r;
      const float v = acc[i][r] + bs;
      if (OUTMODE == 0) {
        ((float*)outp)[(size_t)pix * CC + n] = v;
      } else {
        const int g = n >> 3, c = n & 7;
        ((bf16_t*)outp)[((size_t)((pix >> 12) * G + g) << 15) +
                        (size_t)(pix & 4095) * GC + c] = (bf16_t)v;
      }
    }
  }
}

// ---------------- K3: fused om GEMM (8 waves x 7 N-tiles) + sampling ----------
// value_g layout: [img][g][y][x][8ch] bf16 (plane = 32768 elems).
__global__ __launch_bounds__(512, 4) void om_sample_mfma_kernel(
    const bf16_t* __restrict__ xdw, const bf16_t* __restrict__ om_wT,
    const float* __restrict__ om_b, const bf16_t* __restrict__ value_g,
    bf16_t* __restrict__ sampled) {
  constexpr int GS = 32;        // elems per group slot (27 used)
  constexpr int ROW = 1032;     // 32*32 + 8 pad; ROW*2B = 2064 = 129*16 (16B aligned)
  __shared__ bf16_t s_om[16][ROW];

  const int lane = threadIdx.x & 63;
  const int wave = threadIdx.x >> 6;  // 0..7
  const int pix0 = blockIdx.x * 16;

  // ---- MFMA phase: om[16][864] = xdw_tile @ om_w + b; wave w owns 7 N-tiles
  {
    const int m = lane & 15;
    const int kq = lane >> 4;
    const bf16_t* Ap = xdw + (size_t)(pix0 + m) * CC + kq * 8;
    const bf16_t* Bp = om_wT + (size_t)(wave * 7 * 16 + m) * CC + kq * 8;
    f32x4 acc[7] = {};
#pragma unroll
    for (int ks = 0; ks < 8; ++ks) {
      const bf16x8 a = *(const bf16x8*)(Ap + ks * 32);
#pragma unroll
      for (int i = 0; i < 7; ++i) {
        const bf16x8 b = *(const bf16x8*)(Bp + (size_t)i * 16 * CC + ks * 32);
        acc[i] = __builtin_amdgcn_mfma_f32_16x16x32_bf16(a, b, acc[i], 0, 0, 0);
      }
    }
#pragma unroll
    for (int i = 0; i < 7; ++i) {
      const int nt = wave * 7 + i;
      if (nt < 54) {
        const int n = nt * 16 + m;
        const float bs = om_b[n];
        const int g = n / 27;
        const int j = n - 27 * g;
#pragma unroll
        for (int r = 0; r < 4; ++r)
          s_om[kq * 4 + r][g * GS + j] = (bf16_t)(acc[i][r] + bs);
      }
    }
  }
  __syncthreads();

  // ---- sampling: lane l -> pixel p = l&15, group g = wave*4 + (l>>4)
  {
    const int p = lane & 15;
    const int g = wave * 4 + (lane >> 4);
    const int pix = pix0 + p;
    const int xw = pix & 63;
    const int y = (pix >> 6) & 63;
    const int img = pix >> 12;
    const bf16_t* plane = value_g + ((size_t)(img * G + g) << 15);

    // read this task's 27 om values via 4x ds_read_b128
    const bf16_t* omp = &s_om[p][g * GS];
    const bf16x8 o0 = *(const bf16x8*)(omp);
    const bf16x8 o1 = *(const bf16x8*)(omp + 8);
    const bf16x8 o2 = *(const bf16x8*)(omp + 16);
    const bf16x8 o3 = *(const bf16x8*)(omp + 24);
    float arr[27];
#pragma unroll
    for (int j = 0; j < 8; ++j) {
      arr[j] = (float)o0[j];
      arr[8 + j] = (float)o1[j];
      arr[16 + j] = (float)o2[j];
    }
#pragma unroll
    for (int j = 0; j < 3; ++j) arr[24 + j] = (float)o3[j];

    float acc[GC];
#pragma unroll
    for (int c = 0; c < GC; ++c) acc[c] = 0.0f;

#pragma unroll
    for (int k = 0; k < 9; ++k) {
      const float px = (float)(xw + (k % 3) - 1) + arr[2 * k];
      const float py = (float)(y + (k / 3) - 1) + arr[2 * k + 1];
      const float mk = arr[18 + k];
      const float x0f = floorf(px), y0f = floorf(py);
      const float tx = px - x0f, ty = py - y0f;
      const int ix = (int)x0f, iy = (int)y0f;

      const float vx0 = (ix >= 0 && ix < WW) ? 1.0f : 0.0f;
      const float vx1 = (ix + 1 >= 0 && ix + 1 < WW) ? 1.0f : 0.0f;
      const float vy0 = (iy >= 0 && iy < HH) ? 1.0f : 0.0f;
      const float vy1 = (iy + 1 >= 0 && iy + 1 < HH) ? 1.0f : 0.0f;
      const int ix0 = min(max(ix, 0), WW - 1);
      const int ix1 = min(max(ix + 1, 0), WW - 1);
      const int iy0 = min(max(iy, 0), HH - 1);
      const int iy1 = min(max(iy + 1, 0), HH - 1);

      const bf16x8 v00 = *(const bf16x8*)(plane + (size_t)(iy0 * WW + ix0) * GC);
      const bf16x8 v01 = *(const bf16x8*)(plane + (size_t)(iy0 * WW + ix1) * GC);
      const bf16x8 v10 = *(const bf16x8*)(plane + (size_t)(iy1 * WW + ix0) * GC);
      const bf16x8 v11 = *(const bf16x8*)(plane + (size_t)(iy1 * WW + ix1) * GC);

      const float w00 = mk * (1.0f - ty) * (1.0f - tx) * vy0 * vx0;
      const float w01 = mk * (1.0f - ty) * tx * vy0 * vx1;
      const float w10 = mk * ty * (1.0f - tx) * vy1 * vx0;
      const float w11 = mk * ty * tx * vy1 * vx1;

#pragma unroll
      for (int c = 0; c < GC; ++c) {
        float s = acc[c];
        s = fmaf(w00, (float)v00[c], s);
        s = fmaf(w01, (float)v01[c], s);
        s = fmaf(w10, (float)v10[c], s);
        s = fmaf(w11, (float)v11[c], s);
        acc[c] = s;
      }
    }

    bf16x8 sv;
#pragma unroll
    for (int c = 0; c < GC; ++c) sv[c] = (bf16_t)acc[c];
    *(bf16x8*)(sampled + (size_t)pix * CC + g * GC) = sv;
  }
}

extern "C" void kernel_launch(void* const* d_in, const int* in_sizes, int n_in,
                              void* d_out, int out_size, void* d_ws, size_t ws_size,
                              hipStream_t stream) {
  const float* x = (const float*)d_in[0];
  const float* dw_w = (const float*)d_in[1];
  const float* dw_b = (const float*)d_in[2];
  const float* om_w = (const float*)d_in[3];
  const float* om_b = (const float*)d_in[4];
  const float* vp_w = (const float*)d_in[5];
  const float* vp_b = (const float*)d_in[6];
  const float* op_w = (const float*)d_in[7];
  float* out = (float*)d_out;

  // workspace layout (bytes)
  char* ws = (char*)d_ws;
  bf16_t* value_g = (bf16_t*)ws;                      // 16,777,216
  bf16_t* xdw = (bf16_t*)(ws + 16777216);             // 16,777,216
  bf16_t* x_bf16 = (bf16_t*)(ws + 33554432);          // 16,777,216
  bf16_t* sampled = x_bf16;  // aliased: x_bf16 dead after K1 (stream-ordered)
  bf16_t* om_wT = (bf16_t*)(ws + 50331648);           // 458,752
  bf16_t* vp_wT = (bf16_t*)(ws + 50790400);           // 131,072
  bf16_t* op_wT = (bf16_t*)(ws + 50921472);           // 131,072

  convert_weights_kernel<<<OMD_PAD + 512, 256, 0, stream>>>(om_w, vp_w, op_w,
                                                            om_wT, vp_wT, op_wT);
  dwconv_row_kernel<<<NN * HH, 256, 0, stream>>>(x, dw_w, dw_b, xdw, x_bf16);
  mfma_gemm256_kernel<true, 1><<<NPIX / 64, 512, 0, stream>>>(x_bf16, vp_wT, vp_b, value_g);
  om_sample_mfma_kernel<<<NPIX / 16, 512, 0, stream>>>(xdw, om_wT, om_b, value_g, sampled);
  mfma_gemm256_kernel<false, 0><<<NPIX / 64, 512, 0, stream>>>(sampled, op_wT, nullptr, out);
}

// Round 6
// 253.888 us; speedup vs baseline: 1.3205x; 1.3205x over previous
//
#include <hip/hip_runtime.h>

// DCNv4 on gfx950 — bf16 MFMA pipeline with FRAGMENT-SWIZZLED operand layouts.
// Key insight (R5): direct-from-global MFMA fragment loads with [row][k] layout
// scatter 64 lanes over 64 cachelines/instr (TA-serialized). All GEMM operands
// are stored in fragment order so every fragment load is base + lane*16B.
//   fragIdx(row, c): c = kq*8 + ks*32 + j  ->  (row>>4)*4096 + ks*512 + lane*8 + j
// K0: weights -> bf16 swizzled
// K2: dwconv3x3 -> xdwF + x_bf16F (swizzled)
// K1: value = x @ vp_w + vp_b      (MFMA M=64, writes group-planar value_g)
// K3: fused om GEMM (swizzled B) -> LDS -> sampling -> sampledF (swizzled)
// K4: out = sampledF @ op_wF       (MFMA M=64, fp32 NHWC out)

typedef __bf16 bf16_t;
typedef bf16_t bf16x8 __attribute__((ext_vector_type(8)));
typedef bf16_t bf16x4 __attribute__((ext_vector_type(4)));
typedef float f32x4 __attribute__((ext_vector_type(4)));

namespace {
constexpr int NN = 8, HH = 64, WW = 64, CC = 256;
constexpr int G = 32, GC = 8, OMD = 864;      // G*9*3
constexpr int NPIX = NN * HH * WW;            // 32768
constexpr int OMD_PAD = 896;                  // 56 tiles of 16 (2 dummy)
}

// fragment-swizzled flat index for a [rows][256] bf16 matrix
__device__ __forceinline__ size_t fragIdx(int row, int c) {
  return ((size_t)(row >> 4) * 4096) + ((c >> 5) * 512) + (((c >> 3) & 3) * 128) +
         ((row & 15) * 8) + (c & 7);
}

// ---------------- K0: weights -> bf16, fragment-swizzled ----------------
// block b: [0,896) om row n=b ; [896,1152) vp row ; [1152,1408) op row. thread=k.
__global__ __launch_bounds__(256) void convert_weights_kernel(
    const float* __restrict__ om_w, const float* __restrict__ vp_w,
    const float* __restrict__ op_w, bf16_t* __restrict__ om_wF,
    bf16_t* __restrict__ vp_wF, bf16_t* __restrict__ op_wF) {
  const int k = threadIdx.x;
  const int b = blockIdx.x;
  if (b < OMD_PAD) {
    const float v = (b < OMD) ? om_w[(size_t)k * OMD + b] : 0.0f;
    om_wF[fragIdx(b, k)] = (bf16_t)v;
  } else if (b < OMD_PAD + 256) {
    const int n = b - OMD_PAD;
    vp_wF[fragIdx(n, k)] = (bf16_t)vp_w[(size_t)k * CC + n];
  } else {
    const int n = b - OMD_PAD - 256;
    op_wF[fragIdx(n, k)] = (bf16_t)op_w[(size_t)k * CC + n];
  }
}

// ---------------- K2: dwconv3x3 sliding-window; block = one image row ----------
// outputs fragment-swizzled xdwF and x_bf16F.
__global__ __launch_bounds__(256) void dwconv_row_kernel(
    const float* __restrict__ x, const float* __restrict__ dw_w,
    const float* __restrict__ dw_b, bf16_t* __restrict__ xdwF,
    bf16_t* __restrict__ x_bf16F) {
  const int t = threadIdx.x;
  const int cq = (t & 63) * 4;   // channel base
  const int seg = t >> 6;        // wave id = x segment (16 px each)
  const int row = blockIdx.x;    // n*64 + y
  const int y = row & 63;
  const bool up = (y > 0), dn = (y < HH - 1);
  const float* xrow = x + (size_t)row * WW * CC + cq;

  const float4 bias = *(const float4*)&dw_b[cq];
  float4 dw[9];
#pragma unroll
  for (int i = 0; i < 9; ++i) dw[i] = *(const float4*)&dw_w[(size_t)i * CC + cq];

  const float4 zero = make_float4(0.f, 0.f, 0.f, 0.f);
  auto loadcol = [&](int xx, float4 c[3]) {
    if (xx < 0 || xx >= WW) { c[0] = c[1] = c[2] = zero; return; }
    c[0] = up ? *(const float4*)(xrow + ((size_t)xx - WW) * CC) : zero;
    c[1] = *(const float4*)(xrow + (size_t)xx * CC);
    c[2] = dn ? *(const float4*)(xrow + ((size_t)xx + WW) * CC) : zero;
  };

  const int x0 = seg * 16;
  float4 cm[3], cc[3], cp[3];
  loadcol(x0 - 1, cm);
  loadcol(x0, cc);

  for (int xx = x0; xx < x0 + 16; ++xx) {
    loadcol(xx + 1, cp);
    float4 a = bias;
#pragma unroll
    for (int r = 0; r < 3; ++r) {
      const float4 w0 = dw[r * 3 + 0], w1 = dw[r * 3 + 1], w2 = dw[r * 3 + 2];
      a.x = fmaf(cm[r].x, w0.x, fmaf(cc[r].x, w1.x, fmaf(cp[r].x, w2.x, a.x)));
      a.y = fmaf(cm[r].y, w0.y, fmaf(cc[r].y, w1.y, fmaf(cp[r].y, w2.y, a.y)));
      a.z = fmaf(cm[r].z, w0.z, fmaf(cc[r].z, w1.z, fmaf(cp[r].z, w2.z, a.z)));
      a.w = fmaf(cm[r].w, w0.w, fmaf(cc[r].w, w1.w, fmaf(cp[r].w, w2.w, a.w)));
    }
    const int pix = row * WW + xx;
    const size_t o = fragIdx(pix, cq);  // cq is 4-aligned -> 4 contiguous elems
    bf16x4 av, cv;
    av[0] = (bf16_t)a.x; av[1] = (bf16_t)a.y; av[2] = (bf16_t)a.z; av[3] = (bf16_t)a.w;
    cv[0] = (bf16_t)cc[1].x; cv[1] = (bf16_t)cc[1].y;
    cv[2] = (bf16_t)cc[1].z; cv[3] = (bf16_t)cc[1].w;
    *(bf16x4*)&xdwF[o] = av;
    *(bf16x4*)&x_bf16F[o] = cv;
#pragma unroll
    for (int r = 0; r < 3; ++r) { cm[r] = cc[r]; cc[r] = cp[r]; }
  }
}

// ---------------- K1/K4: 256->256 GEMM, M=64/block, 8 waves, swizzled A/B ------
// wave: (m-tile = w>>1 of 4, n-half = w&1); acc[8] f32x4.
// OUTMODE 0: fp32 NHWC out. OUTMODE 1: bf16 group-planar value_g out.
template <bool HAS_BIAS, int OUTMODE>
__global__ __launch_bounds__(512, 4) void mfma_gemm256_kernel(
    const bf16_t* __restrict__ AF, const bf16_t* __restrict__ BF,
    const float* __restrict__ bias, void* __restrict__ outp) {
  const int lane = threadIdx.x & 63;
  const int wave = threadIdx.x >> 6;
  const int mq = wave >> 1;
  const int nh = wave & 1;
  const int mt = blockIdx.x * 4 + mq;       // m-tile index (16 pixels)
  const int m = lane & 15;
  const int kq = lane >> 4;

  const bf16_t* Ap = AF + (size_t)mt * 4096 + lane * 8;
  const bf16_t* Bp = BF + (size_t)(nh * 8) * 4096 + lane * 8;

  f32x4 acc[8] = {};
#pragma unroll
  for (int ks = 0; ks < 8; ++ks) {
    const bf16x8 a = *(const bf16x8*)(Ap + ks * 512);
#pragma unroll
    for (int i = 0; i < 8; ++i) {
      const bf16x8 b = *(const bf16x8*)(Bp + (size_t)i * 4096 + ks * 512);
      acc[i] = __builtin_amdgcn_mfma_f32_16x16x32_bf16(a, b, acc[i], 0, 0, 0);
    }
  }

  const int row0 = mt * 16 + kq * 4;
#pragma unroll
  for (int i = 0; i < 8; ++i) {
    const int n = (nh * 8 + i) * 16 + m;
    const float bs = HAS_BIAS ? bias[n] : 0.0f;
#pragma unroll
    for (int r = 0; r < 4; ++r) {
      const int pix = row0 + r;
      const float v = acc[i][r] + bs;
      if (OUTMODE == 0) {
        ((float*)outp)[(size_t)pix * CC + n] = v;
      } else {
        const int g = n >> 3, c = n & 7;
        ((bf16_t*)outp)[((size_t)((pix >> 12) * G + g) << 15) +
                        (size_t)(pix & 4095) * GC + c] = (bf16_t)v;
      }
    }
  }
}

// ---------------- K3: fused om GEMM (swizzled B) + sampling ----------
// value_g layout: [img][g][y][x][8ch] bf16. sampled written fragment-swizzled.
__global__ __launch_bounds__(512, 4) void om_sample_mfma_kernel(
    const bf16_t* __restrict__ xdwF, const bf16_t* __restrict__ om_wF,
    const float* __restrict__ om_b, const bf16_t* __restrict__ value_g,
    bf16_t* __restrict__ sampledF) {
  constexpr int GS = 32;        // elems per group slot (27 used)
  constexpr int ROW = 1032;     // 32*32 + 8 pad
  __shared__ bf16_t s_om[16][ROW];

  const int lane = threadIdx.x & 63;
  const int wave = threadIdx.x >> 6;  // 0..7
  const int pix0 = blockIdx.x * 16;

  // ---- MFMA phase: om[16][864] = xdw_tile @ om_w + b; wave w owns 7 N-tiles
  {
    const int m = lane & 15;
    const int kq = lane >> 4;
    const bf16_t* Ap = xdwF + (size_t)blockIdx.x * 4096 + lane * 8;
    const bf16_t* Bp = om_wF + (size_t)(wave * 7) * 4096 + lane * 8;
    f32x4 acc[7] = {};
#pragma unroll
    for (int ks = 0; ks < 8; ++ks) {
      const bf16x8 a = *(const bf16x8*)(Ap + ks * 512);
#pragma unroll
      for (int i = 0; i < 7; ++i) {
        const bf16x8 b = *(const bf16x8*)(Bp + (size_t)i * 4096 + ks * 512);
        acc[i] = __builtin_amdgcn_mfma_f32_16x16x32_bf16(a, b, acc[i], 0, 0, 0);
      }
    }
#pragma unroll
    for (int i = 0; i < 7; ++i) {
      const int nt = wave * 7 + i;
      if (nt < 54) {
        const int n = nt * 16 + m;
        const float bs = om_b[n];
        const int g = n / 27;
        const int j = n - 27 * g;
#pragma unroll
        for (int r = 0; r < 4; ++r)
          s_om[kq * 4 + r][g * GS + j] = (bf16_t)(acc[i][r] + bs);
      }
    }
  }
  __syncthreads();

  // ---- sampling: lane l -> pixel p = l&15, group g = wave*4 + (l>>4)
  {
    const int p = lane & 15;
    const int g = wave * 4 + (lane >> 4);
    const int pix = pix0 + p;
    const int xw = pix & 63;
    const int y = (pix >> 6) & 63;
    const int img = pix >> 12;
    const bf16_t* plane = value_g + ((size_t)(img * G + g) << 15);

    const bf16_t* omp = &s_om[p][g * GS];
    const bf16x8 o0 = *(const bf16x8*)(omp);
    const bf16x8 o1 = *(const bf16x8*)(omp + 8);
    const bf16x8 o2 = *(const bf16x8*)(omp + 16);
    const bf16x8 o3 = *(const bf16x8*)(omp + 24);
    float arr[27];
#pragma unroll
    for (int j = 0; j < 8; ++j) {
      arr[j] = (float)o0[j];
      arr[8 + j] = (float)o1[j];
      arr[16 + j] = (float)o2[j];
    }
#pragma unroll
    for (int j = 0; j < 3; ++j) arr[24 + j] = (float)o3[j];

    float acc[GC];
#pragma unroll
    for (int c = 0; c < GC; ++c) acc[c] = 0.0f;

#pragma unroll
    for (int k = 0; k < 9; ++k) {
      const float px = (float)(xw + (k % 3) - 1) + arr[2 * k];
      const float py = (float)(y + (k / 3) - 1) + arr[2 * k + 1];
      const float mk = arr[18 + k];
      const float x0f = floorf(px), y0f = floorf(py);
      const float tx = px - x0f, ty = py - y0f;
      const int ix = (int)x0f, iy = (int)y0f;

      const float vx0 = (ix >= 0 && ix < WW) ? 1.0f : 0.0f;
      const float vx1 = (ix + 1 >= 0 && ix + 1 < WW) ? 1.0f : 0.0f;
      const float vy0 = (iy >= 0 && iy < HH) ? 1.0f : 0.0f;
      const float vy1 = (iy + 1 >= 0 && iy + 1 < HH) ? 1.0f : 0.0f;
      const int ix0 = min(max(ix, 0), WW - 1);
      const int ix1 = min(max(ix + 1, 0), WW - 1);
      const int iy0 = min(max(iy, 0), HH - 1);
      const int iy1 = min(max(iy + 1, 0), HH - 1);

      const bf16x8 v00 = *(const bf16x8*)(plane + (size_t)(iy0 * WW + ix0) * GC);
      const bf16x8 v01 = *(const bf16x8*)(plane + (size_t)(iy0 * WW + ix1) * GC);
      const bf16x8 v10 = *(const bf16x8*)(plane + (size_t)(iy1 * WW + ix0) * GC);
      const bf16x8 v11 = *(const bf16x8*)(plane + (size_t)(iy1 * WW + ix1) * GC);

      const float w00 = mk * (1.0f - ty) * (1.0f - tx) * vy0 * vx0;
      const float w01 = mk * (1.0f - ty) * tx * vy0 * vx1;
      const float w10 = mk * ty * (1.0f - tx) * vy1 * vx0;
      const float w11 = mk * ty * tx * vy1 * vx1;

#pragma unroll
      for (int c = 0; c < GC; ++c) {
        float s = acc[c];
        s = fmaf(w00, (float)v00[c], s);
        s = fmaf(w01, (float)v01[c], s);
        s = fmaf(w10, (float)v10[c], s);
        s = fmaf(w11, (float)v11[c], s);
        acc[c] = s;
      }
    }

    bf16x8 sv;
#pragma unroll
    for (int c = 0; c < GC; ++c) sv[c] = (bf16_t)acc[c];
    // fragment-swizzled store: for c = g*8+j -> ks=g>>2 (==wave), kq=g&3:
    // flat = pb*4096 + wave*512 + (lane>>4)*128 + p*8 + j = pb*4096 + wave*512 + lane*8
    *(bf16x8*)(sampledF + (size_t)blockIdx.x * 4096 + wave * 512 + lane * 8) = sv;
  }
}

extern "C" void kernel_launch(void* const* d_in, const int* in_sizes, int n_in,
                              void* d_out, int out_size, void* d_ws, size_t ws_size,
                              hipStream_t stream) {
  const float* x = (const float*)d_in[0];
  const float* dw_w = (const float*)d_in[1];
  const float* dw_b = (const float*)d_in[2];
  const float* om_w = (const float*)d_in[3];
  const float* om_b = (const float*)d_in[4];
  const float* vp_w = (const float*)d_in[5];
  const float* vp_b = (const float*)d_in[6];
  const float* op_w = (const float*)d_in[7];
  float* out = (float*)d_out;

  // workspace layout (bytes)
  char* ws = (char*)d_ws;
  bf16_t* value_g = (bf16_t*)ws;                      // 16,777,216
  bf16_t* xdwF = (bf16_t*)(ws + 16777216);            // 16,777,216
  bf16_t* x_bf16F = (bf16_t*)(ws + 33554432);         // 16,777,216
  bf16_t* sampledF = x_bf16F;  // aliased: x_bf16F dead after K1 (stream-ordered)
  bf16_t* om_wF = (bf16_t*)(ws + 50331648);           // 458,752
  bf16_t* vp_wF = (bf16_t*)(ws + 50790400);           // 131,072
  bf16_t* op_wF = (bf16_t*)(ws + 50921472);           // 131,072

  convert_weights_kernel<<<OMD_PAD + 512, 256, 0, stream>>>(om_w, vp_w, op_w,
                                                            om_wF, vp_wF, op_wF);
  dwconv_row_kernel<<<NN * HH, 256, 0, stream>>>(x, dw_w, dw_b, xdwF, x_bf16F);
  mfma_gemm256_kernel<true, 1><<<NPIX / 64, 512, 0, stream>>>(x_bf16F, vp_wF, vp_b, value_g);
  om_sample_mfma_kernel<<<NPIX / 16, 512, 0, stream>>>(xdwF, om_wF, om_b, value_g, sampledF);
  mfma_gemm256_kernel<false, 0><<<NPIX / 64, 512, 0, stream>>>(sampledF, op_wF, nullptr, out);
}

// Round 7
// 230.475 us; speedup vs baseline: 1.4547x; 1.1016x over previous
//
#include <hip/hip_runtime.h>

// DCNv4 on gfx950 — bf16 MFMA pipeline, fragment-swizzled operands (R5),
// R6: coalesced weight transpose, LDS-repacked value_g stores, half-row
// dwconv blocks, M=32 om-GEMM tile (B-fragment reuse).

typedef __bf16 bf16_t;
typedef bf16_t bf16x8 __attribute__((ext_vector_type(8)));
typedef bf16_t bf16x4 __attribute__((ext_vector_type(4)));
typedef float f32x4 __attribute__((ext_vector_type(4)));

namespace {
constexpr int NN = 8, HH = 64, WW = 64, CC = 256;
constexpr int G = 32, GC = 8, OMD = 864;      // G*9*3
constexpr int NPIX = NN * HH * WW;            // 32768
constexpr int OMD_PAD = 896;                  // 56 tiles of 16 (2 dummy)
}

// fragment-swizzled flat index for a [rows][256] bf16 matrix
__device__ __forceinline__ size_t fragIdx(int row, int c) {
  return ((size_t)(row >> 4) * 4096) + ((c >> 5) * 512) + (((c >> 3) & 3) * 128) +
         ((row & 15) * 8) + (c & 7);
}

// ---------------- K0: weights -> bf16 fragment-swizzled, via LDS transpose ----
// 64n x 64k tile per block. Coalesced reads (lanes along n) and coalesced
// 16B/lane fragment writes. blocks: 56 om + 16 vp + 16 op.
__global__ __launch_bounds__(256) void convert_weights_kernel(
    const float* __restrict__ om_w, const float* __restrict__ vp_w,
    const float* __restrict__ op_w, bf16_t* __restrict__ om_wF,
    bf16_t* __restrict__ vp_wF, bf16_t* __restrict__ op_wF) {
  __shared__ float s_t[64][65];
  const int b = blockIdx.x, t = threadIdx.x;
  const float* src;
  bf16_t* dst;
  int ld, ncols, nt, kt;
  if (b < 56) {
    src = om_w; dst = om_wF; ld = OMD; ncols = OMD; kt = b / 14; nt = b % 14;
  } else if (b < 72) {
    const int i = b - 56;
    src = vp_w; dst = vp_wF; ld = CC; ncols = CC; kt = i >> 2; nt = i & 3;
  } else {
    const int i = b - 72;
    src = op_w; dst = op_wF; ld = CC; ncols = CC; kt = i >> 2; nt = i & 3;
  }
  const int nl = t & 63, kh = t >> 6;
  const int n = nt * 64 + nl;
#pragma unroll
  for (int i = 0; i < 16; ++i) {
    const int kl = kh * 16 + i;
    s_t[kl][nl] = (n < ncols) ? src[(size_t)(kt * 64 + kl) * ld + n] : 0.0f;
  }
  __syncthreads();
  const int lane = t & 63, kq = lane >> 4, n15 = lane & 15, n16 = t >> 6;
#pragma unroll
  for (int it = 0; it < 2; ++it) {
    bf16x8 v;
#pragma unroll
    for (int j = 0; j < 8; ++j) v[j] = (bf16_t)s_t[it * 32 + kq * 8 + j][n16 * 16 + n15];
    const size_t off = (size_t)(nt * 4 + n16) * 4096 + (size_t)(kt * 2 + it) * 512 +
                       kq * 128 + n15 * 8;
    *(bf16x8*)(dst + off) = v;
  }
}

// ---------------- K2: dwconv3x3 sliding-window; block = half image row --------
__global__ __launch_bounds__(256) void dwconv_row_kernel(
    const float* __restrict__ x, const float* __restrict__ dw_w,
    const float* __restrict__ dw_b, bf16_t* __restrict__ xdwF,
    bf16_t* __restrict__ x_bf16F) {
  const int t = threadIdx.x;
  const int cq = (t & 63) * 4;   // channel base
  const int seg = t >> 6;        // wave id = x segment (8 px each)
  const int row = blockIdx.x >> 1;   // n*64 + y
  const int half = blockIdx.x & 1;
  const int y = row & 63;
  const bool up = (y > 0), dn = (y < HH - 1);
  const float* xrow = x + (size_t)row * WW * CC + cq;

  const float4 bias = *(const float4*)&dw_b[cq];
  float4 dw[9];
#pragma unroll
  for (int i = 0; i < 9; ++i) dw[i] = *(const float4*)&dw_w[(size_t)i * CC + cq];

  const float4 zero = make_float4(0.f, 0.f, 0.f, 0.f);
  auto loadcol = [&](int xx, float4 c[3]) {
    if (xx < 0 || xx >= WW) { c[0] = c[1] = c[2] = zero; return; }
    c[0] = up ? *(const float4*)(xrow + ((size_t)xx - WW) * CC) : zero;
    c[1] = *(const float4*)(xrow + (size_t)xx * CC);
    c[2] = dn ? *(const float4*)(xrow + ((size_t)xx + WW) * CC) : zero;
  };

  const int x0 = half * 32 + seg * 8;
  float4 cm[3], cc[3], cp[3];
  loadcol(x0 - 1, cm);
  loadcol(x0, cc);

  for (int xx = x0; xx < x0 + 8; ++xx) {
    loadcol(xx + 1, cp);
    float4 a = bias;
#pragma unroll
    for (int r = 0; r < 3; ++r) {
      const float4 w0 = dw[r * 3 + 0], w1 = dw[r * 3 + 1], w2 = dw[r * 3 + 2];
      a.x = fmaf(cm[r].x, w0.x, fmaf(cc[r].x, w1.x, fmaf(cp[r].x, w2.x, a.x)));
      a.y = fmaf(cm[r].y, w0.y, fmaf(cc[r].y, w1.y, fmaf(cp[r].y, w2.y, a.y)));
      a.z = fmaf(cm[r].z, w0.z, fmaf(cc[r].z, w1.z, fmaf(cp[r].z, w2.z, a.z)));
      a.w = fmaf(cm[r].w, w0.w, fmaf(cc[r].w, w1.w, fmaf(cp[r].w, w2.w, a.w)));
    }
    const int pix = row * WW + xx;
    const size_t o = fragIdx(pix, cq);
    bf16x4 av, cv;
    av[0] = (bf16_t)a.x; av[1] = (bf16_t)a.y; av[2] = (bf16_t)a.z; av[3] = (bf16_t)a.w;
    cv[0] = (bf16_t)cc[1].x; cv[1] = (bf16_t)cc[1].y;
    cv[2] = (bf16_t)cc[1].z; cv[3] = (bf16_t)cc[1].w;
    *(bf16x4*)&xdwF[o] = av;
    *(bf16x4*)&x_bf16F[o] = cv;
#pragma unroll
    for (int r = 0; r < 3; ++r) { cm[r] = cc[r]; cc[r] = cp[r]; }
  }
}

// ---------------- K1/K4: 256->256 GEMM, M=64/block, 8 waves, swizzled A/B ------
// OUTMODE 0: fp32 NHWC out (direct). OUTMODE 1: bf16 group-planar value_g out
// via LDS repack (coalesced 16B/lane stores).
template <bool HAS_BIAS, int OUTMODE>
__global__ __launch_bounds__(512, 4) void mfma_gemm256_kernel(
    const bf16_t* __restrict__ AF, const bf16_t* __restrict__ BF,
    const float* __restrict__ bias, void* __restrict__ outp) {
  __shared__ bf16_t s_val[OUTMODE == 1 ? 64 : 1][OUTMODE == 1 ? 264 : 1];
  const int lane = threadIdx.x & 63;
  const int wave = threadIdx.x >> 6;
  const int mq = wave >> 1;
  const int nh = wave & 1;
  const int mt = blockIdx.x * 4 + mq;       // m-tile index (16 pixels)
  const int m = lane & 15;
  const int kq = lane >> 4;

  const bf16_t* Ap = AF + (size_t)mt * 4096 + lane * 8;
  const bf16_t* Bp = BF + (size_t)(nh * 8) * 4096 + lane * 8;

  f32x4 acc[8] = {};
#pragma unroll
  for (int ks = 0; ks < 8; ++ks) {
    const bf16x8 a = *(const bf16x8*)(Ap + ks * 512);
#pragma unroll
    for (int i = 0; i < 8; ++i) {
      const bf16x8 b = *(const bf16x8*)(Bp + (size_t)i * 4096 + ks * 512);
      acc[i] = __builtin_amdgcn_mfma_f32_16x16x32_bf16(a, b, acc[i], 0, 0, 0);
    }
  }

#pragma unroll
  for (int i = 0; i < 8; ++i) {
    const int n = (nh * 8 + i) * 16 + m;
    const float bs = HAS_BIAS ? bias[n] : 0.0f;
#pragma unroll
    for (int r = 0; r < 4; ++r) {
      const float v = acc[i][r] + bs;
      if (OUTMODE == 0) {
        const int pix = mt * 16 + kq * 4 + r;
        ((float*)outp)[(size_t)pix * CC + n] = v;
      } else {
        const int pl = mq * 16 + kq * 4 + r;  // pixel local 0..63
        s_val[pl][n] = (bf16_t)v;
      }
    }
  }

  if (OUTMODE == 1) {
    __syncthreads();
    const int p16 = lane & 15;
    const int gl = lane >> 4;        // 0..3
    const int pt = wave & 3;         // pixel 16-tile
    const int gh = wave >> 2;        // 0..1
    const int pl = pt * 16 + p16;
    const int pixg = blockIdx.x * 64 + pl;
    const int img = pixg >> 12;
    bf16_t* vg = (bf16_t*)outp;
#pragma unroll
    for (int i = 0; i < 4; ++i) {
      const int g = i * 8 + gh * 4 + gl;
      const bf16x8 v = *(const bf16x8*)&s_val[pl][g * 8];
      *(bf16x8*)(vg + ((size_t)(img * G + g) << 15) + (size_t)(pixg & 4095) * GC) = v;
    }
  }
}

// ---------------- K3: fused om GEMM (M=32, B reuse) + sampling ----------
// value_g layout: [img][g][y][x][8ch] bf16. sampled written fragment-swizzled.
__global__ __launch_bounds__(512, 4) void om_sample_mfma_kernel(
    const bf16_t* __restrict__ xdwF, const bf16_t* __restrict__ om_wF,
    const float* __restrict__ om_b, const bf16_t* __restrict__ value_g,
    bf16_t* __restrict__ sampledF) {
  constexpr int GS = 32;  // elems per group slot (27 used)
  __shared__ bf16_t s_om[32][1024];  // 64 KB

  const int lane = threadIdx.x & 63;
  const int wave = threadIdx.x >> 6;  // 0..7
  const int pix0 = blockIdx.x * 32;

  // ---- MFMA phase: om[32][864]; wave w owns 7 N-tiles x 2 m-tiles (B reused)
  {
    const int m = lane & 15;
    const int kq = lane >> 4;
    const bf16_t* Ap = xdwF + (size_t)(blockIdx.x * 2) * 4096 + lane * 8;
    const bf16_t* Bp = om_wF + (size_t)(wave * 7) * 4096 + lane * 8;
    f32x4 acc[2][7] = {};
#pragma unroll
    for (int ks = 0; ks < 8; ++ks) {
      const bf16x8 a0 = *(const bf16x8*)(Ap + ks * 512);
      const bf16x8 a1 = *(const bf16x8*)(Ap + 4096 + ks * 512);
#pragma unroll
      for (int i = 0; i < 7; ++i) {
        const bf16x8 b = *(const bf16x8*)(Bp + (size_t)i * 4096 + ks * 512);
        acc[0][i] = __builtin_amdgcn_mfma_f32_16x16x32_bf16(a0, b, acc[0][i], 0, 0, 0);
        acc[1][i] = __builtin_amdgcn_mfma_f32_16x16x32_bf16(a1, b, acc[1][i], 0, 0, 0);
      }
    }
#pragma unroll
    for (int i = 0; i < 7; ++i) {
      const int nt = wave * 7 + i;
      if (nt < 54) {
        const int n = nt * 16 + m;
        const float bs = om_b[n];
        const int g = n / 27;
        const int j = n - 27 * g;
#pragma unroll
        for (int mt2 = 0; mt2 < 2; ++mt2)
#pragma unroll
          for (int r = 0; r < 4; ++r)
            s_om[mt2 * 16 + kq * 4 + r][g * GS + j] = (bf16_t)(acc[mt2][i][r] + bs);
      }
    }
  }
  __syncthreads();

  // ---- sampling: 32 px x 32 g = 1024 tasks, 2/thread
  const int gl = lane >> 4;
  const int g = wave * 4 + gl;
#pragma unroll
  for (int iter = 0; iter < 2; ++iter) {
    const int p = (lane & 15) + iter * 16;
    const int pix = pix0 + p;
    const int xw = pix & 63;
    const int y = (pix >> 6) & 63;
    const int img = pix >> 12;
    const bf16_t* plane = value_g + ((size_t)(img * G + g) << 15);

    const bf16_t* omp = &s_om[p][g * GS];
    const bf16x8 o0 = *(const bf16x8*)(omp);
    const bf16x8 o1 = *(const bf16x8*)(omp + 8);
    const bf16x8 o2 = *(const bf16x8*)(omp + 16);
    const bf16x8 o3 = *(const bf16x8*)(omp + 24);
    float arr[27];
#pragma unroll
    for (int j = 0; j < 8; ++j) {
      arr[j] = (float)o0[j];
      arr[8 + j] = (float)o1[j];
      arr[16 + j] = (float)o2[j];
    }
#pragma unroll
    for (int j = 0; j < 3; ++j) arr[24 + j] = (float)o3[j];

    float acc[GC];
#pragma unroll
    for (int c = 0; c < GC; ++c) acc[c] = 0.0f;

#pragma unroll
    for (int k = 0; k < 9; ++k) {
      const float px = (float)(xw + (k % 3) - 1) + arr[2 * k];
      const float py = (float)(y + (k / 3) - 1) + arr[2 * k + 1];
      const float mk = arr[18 + k];
      const float x0f = floorf(px), y0f = floorf(py);
      const float tx = px - x0f, ty = py - y0f;
      const int ix = (int)x0f, iy = (int)y0f;

      const float vx0 = (ix >= 0 && ix < WW) ? 1.0f : 0.0f;
      const float vx1 = (ix + 1 >= 0 && ix + 1 < WW) ? 1.0f : 0.0f;
      const float vy0 = (iy >= 0 && iy < HH) ? 1.0f : 0.0f;
      const float vy1 = (iy + 1 >= 0 && iy + 1 < HH) ? 1.0f : 0.0f;
      const int ix0 = min(max(ix, 0), WW - 1);
      const int ix1 = min(max(ix + 1, 0), WW - 1);
      const int iy0 = min(max(iy, 0), HH - 1);
      const int iy1 = min(max(iy + 1, 0), HH - 1);

      const bf16x8 v00 = *(const bf16x8*)(plane + (size_t)(iy0 * WW + ix0) * GC);
      const bf16x8 v01 = *(const bf16x8*)(plane + (size_t)(iy0 * WW + ix1) * GC);
      const bf16x8 v10 = *(const bf16x8*)(plane + (size_t)(iy1 * WW + ix0) * GC);
      const bf16x8 v11 = *(const bf16x8*)(plane + (size_t)(iy1 * WW + ix1) * GC);

      const float w00 = mk * (1.0f - ty) * (1.0f - tx) * vy0 * vx0;
      const float w01 = mk * (1.0f - ty) * tx * vy0 * vx1;
      const float w10 = mk * ty * (1.0f - tx) * vy1 * vx0;
      const float w11 = mk * ty * tx * vy1 * vx1;

#pragma unroll
      for (int c = 0; c < GC; ++c) {
        float s = acc[c];
        s = fmaf(w00, (float)v00[c], s);
        s = fmaf(w01, (float)v01[c], s);
        s = fmaf(w10, (float)v10[c], s);
        s = fmaf(w11, (float)v11[c], s);
        acc[c] = s;
      }
    }

    bf16x8 sv;
#pragma unroll
    for (int c = 0; c < GC; ++c) sv[c] = (bf16_t)acc[c];
    // fragment-swizzled store: pb = blockIdx*2 + iter; ks=wave, kq=gl, row=p&15
    *(bf16x8*)(sampledF + (size_t)(blockIdx.x * 2 + iter) * 4096 + wave * 512 +
               lane * 8) = sv;
  }
}

extern "C" void kernel_launch(void* const* d_in, const int* in_sizes, int n_in,
                              void* d_out, int out_size, void* d_ws, size_t ws_size,
                              hipStream_t stream) {
  const float* x = (const float*)d_in[0];
  const float* dw_w = (const float*)d_in[1];
  const float* dw_b = (const float*)d_in[2];
  const float* om_w = (const float*)d_in[3];
  const float* om_b = (const float*)d_in[4];
  const float* vp_w = (const float*)d_in[5];
  const float* vp_b = (const float*)d_in[6];
  const float* op_w = (const float*)d_in[7];
  float* out = (float*)d_out;

  // workspace layout (bytes)
  char* ws = (char*)d_ws;
  bf16_t* value_g = (bf16_t*)ws;                      // 16,777,216
  bf16_t* xdwF = (bf16_t*)(ws + 16777216);            // 16,777,216
  bf16_t* x_bf16F = (bf16_t*)(ws + 33554432);         // 16,777,216
  bf16_t* sampledF = x_bf16F;  // aliased: x_bf16F dead after K1 (stream-ordered)
  bf16_t* om_wF = (bf16_t*)(ws + 50331648);           // 458,752
  bf16_t* vp_wF = (bf16_t*)(ws + 50790400);           // 131,072
  bf16_t* op_wF = (bf16_t*)(ws + 50921472);           // 131,072

  convert_weights_kernel<<<88, 256, 0, stream>>>(om_w, vp_w, op_w,
                                                 om_wF, vp_wF, op_wF);
  dwconv_row_kernel<<<NN * HH * 2, 256, 0, stream>>>(x, dw_w, dw_b, xdwF, x_bf16F);
  mfma_gemm256_kernel<true, 1><<<NPIX / 64, 512, 0, stream>>>(x_bf16F, vp_wF, vp_b, value_g);
  om_sample_mfma_kernel<<<NPIX / 32, 512, 0, stream>>>(xdwF, om_wF, om_b, value_g, sampledF);
  mfma_gemm256_kernel<false, 0><<<NPIX / 64, 512, 0, stream>>>(sampledF, op_wF, nullptr, out);
}

// Round 8
// 212.059 us; speedup vs baseline: 1.5810x; 1.0868x over previous
//
#include <hip/hip_runtime.h>

// DCNv4 on gfx950 — bf16 MFMA pipeline, fragment-swizzled operands.
// R7: K2+K1 fused (dwconv -> LDS x-frags -> value GEMM), K3 s_om rotation
// swizzle (16-way -> ~4-way bank conflicts).
// KW: weights -> bf16 fragment-swizzled
// KF: dwconv3x3 + value GEMM (block = image row) -> xdwF, value_g
// K3: om GEMM (M=32, B reuse) -> LDS -> sampling -> sampledF
// K4: out = sampledF @ op_wF (M=64, fp32 NHWC out)

typedef __bf16 bf16_t;
typedef bf16_t bf16x8 __attribute__((ext_vector_type(8)));
typedef bf16_t bf16x4 __attribute__((ext_vector_type(4)));
typedef float f32x4 __attribute__((ext_vector_type(4)));

namespace {
constexpr int NN = 8, HH = 64, WW = 64, CC = 256;
constexpr int G = 32, GC = 8, OMD = 864;      // G*9*3
constexpr int NPIX = NN * HH * WW;            // 32768
}

// fragment-swizzled flat index for a [rows][256] bf16 matrix
__device__ __forceinline__ size_t fragIdx(int row, int c) {
  return ((size_t)(row >> 4) * 4096) + ((c >> 5) * 512) + (((c >> 3) & 3) * 128) +
         ((row & 15) * 8) + (c & 7);
}

// ---------------- KW: weights -> bf16 fragment-swizzled, via LDS transpose ----
__global__ __launch_bounds__(256) void convert_weights_kernel(
    const float* __restrict__ om_w, const float* __restrict__ vp_w,
    const float* __restrict__ op_w, bf16_t* __restrict__ om_wF,
    bf16_t* __restrict__ vp_wF, bf16_t* __restrict__ op_wF) {
  __shared__ float s_t[64][65];
  const int b = blockIdx.x, t = threadIdx.x;
  const float* src;
  bf16_t* dst;
  int ld, ncols, nt, kt;
  if (b < 56) {
    src = om_w; dst = om_wF; ld = OMD; ncols = OMD; kt = b / 14; nt = b % 14;
  } else if (b < 72) {
    const int i = b - 56;
    src = vp_w; dst = vp_wF; ld = CC; ncols = CC; kt = i >> 2; nt = i & 3;
  } else {
    const int i = b - 72;
    src = op_w; dst = op_wF; ld = CC; ncols = CC; kt = i >> 2; nt = i & 3;
  }
  const int nl = t & 63, kh = t >> 6;
  const int n = nt * 64 + nl;
#pragma unroll
  for (int i = 0; i < 16; ++i) {
    const int kl = kh * 16 + i;
    s_t[kl][nl] = (n < ncols) ? src[(size_t)(kt * 64 + kl) * ld + n] : 0.0f;
  }
  __syncthreads();
  const int lane = t & 63, kq = lane >> 4, n15 = lane & 15, n16 = t >> 6;
#pragma unroll
  for (int it = 0; it < 2; ++it) {
    bf16x8 v;
#pragma unroll
    for (int j = 0; j < 8; ++j) v[j] = (bf16_t)s_t[it * 32 + kq * 8 + j][n16 * 16 + n15];
    const size_t off = (size_t)(nt * 4 + n16) * 4096 + (size_t)(kt * 2 + it) * 512 +
                       kq * 128 + n15 * 8;
    *(bf16x8*)(dst + off) = v;
  }
}

// ---------------- KF: fused dwconv3x3 + value GEMM; block = one image row ----
// Phase A: sliding-window dwconv (8 px/thread) -> xdwF (global, frag layout)
//          and x center bf16 -> LDS in fragment layout (64x256 = 32 KB).
// Phase B: value = x @ vp_w + vp_b, A-frags from LDS, M=64, 8 waves.
//          Writes value_g planar [img][g][4096][8c] bf16.
__global__ __launch_bounds__(512, 4) void dwconv_value_kernel(
    const float* __restrict__ x, const float* __restrict__ dw_w,
    const float* __restrict__ dw_b, const bf16_t* __restrict__ vp_wF,
    const float* __restrict__ vp_b, bf16_t* __restrict__ xdwF,
    bf16_t* __restrict__ value_g) {
  __shared__ bf16_t s_xf[64 * 256];  // x bf16 fragments for this row's 4 m-tiles

  const int t = threadIdx.x;
  const int row = blockIdx.x;        // img*64 + y
  const int y = row & 63;
  const int img = row >> 6;

  // ---- Phase A: dwconv
  {
    const int cq = (t & 63) * 4;   // channel base
    const int seg = t >> 6;        // 8-px segment
    const bool up = (y > 0), dn = (y < HH - 1);
    const float* xrow = x + (size_t)row * WW * CC + cq;

    const float4 bias = *(const float4*)&dw_b[cq];
    float4 dw[9];
#pragma unroll
    for (int i = 0; i < 9; ++i) dw[i] = *(const float4*)&dw_w[(size_t)i * CC + cq];

    const float4 zero = make_float4(0.f, 0.f, 0.f, 0.f);
    auto loadcol = [&](int xx, float4 c[3]) {
      if (xx < 0 || xx >= WW) { c[0] = c[1] = c[2] = zero; return; }
      c[0] = up ? *(const float4*)(xrow + ((size_t)xx - WW) * CC) : zero;
      c[1] = *(const float4*)(xrow + (size_t)xx * CC);
      c[2] = dn ? *(const float4*)(xrow + ((size_t)xx + WW) * CC) : zero;
    };

    const int x0 = seg * 8;
    float4 cm[3], cc[3], cp[3];
    loadcol(x0 - 1, cm);
    loadcol(x0, cc);

    for (int xx = x0; xx < x0 + 8; ++xx) {
      loadcol(xx + 1, cp);
      float4 a = bias;
#pragma unroll
      for (int r = 0; r < 3; ++r) {
        const float4 w0 = dw[r * 3 + 0], w1 = dw[r * 3 + 1], w2 = dw[r * 3 + 2];
        a.x = fmaf(cm[r].x, w0.x, fmaf(cc[r].x, w1.x, fmaf(cp[r].x, w2.x, a.x)));
        a.y = fmaf(cm[r].y, w0.y, fmaf(cc[r].y, w1.y, fmaf(cp[r].y, w2.y, a.y)));
        a.z = fmaf(cm[r].z, w0.z, fmaf(cc[r].z, w1.z, fmaf(cp[r].z, w2.z, a.z)));
        a.w = fmaf(cm[r].w, w0.w, fmaf(cc[r].w, w1.w, fmaf(cp[r].w, w2.w, a.w)));
      }
      const int pix = row * WW + xx;
      bf16x4 av, cv;
      av[0] = (bf16_t)a.x; av[1] = (bf16_t)a.y; av[2] = (bf16_t)a.z; av[3] = (bf16_t)a.w;
      cv[0] = (bf16_t)cc[1].x; cv[1] = (bf16_t)cc[1].y;
      cv[2] = (bf16_t)cc[1].z; cv[3] = (bf16_t)cc[1].w;
      *(bf16x4*)&xdwF[fragIdx(pix, cq)] = av;
      // local fragment index for pixel xx (0..63) within this row tile
      const int lf = (xx >> 4) * 4096 + ((cq >> 5) * 512) + (((cq >> 3) & 3) * 128) +
                     ((xx & 15) * 8) + (cq & 7);
      *(bf16x4*)&s_xf[lf] = cv;
#pragma unroll
      for (int r = 0; r < 3; ++r) { cm[r] = cc[r]; cc[r] = cp[r]; }
    }
  }
  __syncthreads();

  // ---- Phase B: value GEMM (M=64 from LDS, N=256)
  {
    const int lane = t & 63;
    const int wave = t >> 6;
    const int mq = wave >> 1;      // m-tile 0..3
    const int nh = wave & 1;       // n-half
    const int m = lane & 15;
    const int kq = lane >> 4;

    const bf16_t* Ap = s_xf + mq * 4096 + lane * 8;
    const bf16_t* Bp = vp_wF + (size_t)(nh * 8) * 4096 + lane * 8;

    f32x4 acc[8] = {};
#pragma unroll
    for (int ks = 0; ks < 8; ++ks) {
      const bf16x8 a = *(const bf16x8*)(Ap + ks * 512);
#pragma unroll
      for (int i = 0; i < 8; ++i) {
        const bf16x8 b = *(const bf16x8*)(Bp + (size_t)i * 4096 + ks * 512);
        acc[i] = __builtin_amdgcn_mfma_f32_16x16x32_bf16(a, b, acc[i], 0, 0, 0);
      }
    }

#pragma unroll
    for (int i = 0; i < 8; ++i) {
      const int n = (nh * 8 + i) * 16 + m;
      const float bs = vp_b[n];
      const int g = n >> 3, c = n & 7;
      bf16_t* plane = value_g + ((size_t)(img * G + g) << 15) + c;
#pragma unroll
      for (int r = 0; r < 4; ++r) {
        const int pl = mq * 16 + kq * 4 + r;           // pixel local 0..63
        const int pin = y * 64 + pl;                   // pixel within image
        plane[(size_t)pin * GC] = (bf16_t)(acc[i][r] + bs);
      }
    }
  }
}

// ---------------- K3: fused om GEMM (M=32, B reuse) + sampling ----------
// s_om rows rotated in 16B chunks by +p to break bank aliasing.
__global__ __launch_bounds__(512, 4) void om_sample_mfma_kernel(
    const bf16_t* __restrict__ xdwF, const bf16_t* __restrict__ om_wF,
    const float* __restrict__ om_b, const bf16_t* __restrict__ value_g,
    bf16_t* __restrict__ sampledF) {
  __shared__ bf16_t s_om[32 * 1024];  // 64 KB; row p: chunk (g*4+c+p)&127

  const int lane = threadIdx.x & 63;
  const int wave = threadIdx.x >> 6;  // 0..7
  const int pix0 = blockIdx.x * 32;

  // ---- MFMA phase: om[32][864]; wave w owns 7 N-tiles x 2 m-tiles (B reused)
  {
    const int m = lane & 15;
    const int kq = lane >> 4;
    const bf16_t* Ap = xdwF + (size_t)(blockIdx.x * 2) * 4096 + lane * 8;
    const bf16_t* Bp = om_wF + (size_t)(wave * 7) * 4096 + lane * 8;
    f32x4 acc[2][7] = {};
#pragma unroll
    for (int ks = 0; ks < 8; ++ks) {
      const bf16x8 a0 = *(const bf16x8*)(Ap + ks * 512);
      const bf16x8 a1 = *(const bf16x8*)(Ap + 4096 + ks * 512);
#pragma unroll
      for (int i = 0; i < 7; ++i) {
        const bf16x8 b = *(const bf16x8*)(Bp + (size_t)i * 4096 + ks * 512);
        acc[0][i] = __builtin_amdgcn_mfma_f32_16x16x32_bf16(a0, b, acc[0][i], 0, 0, 0);
        acc[1][i] = __builtin_amdgcn_mfma_f32_16x16x32_bf16(a1, b, acc[1][i], 0, 0, 0);
      }
    }
#pragma unroll
    for (int i = 0; i < 7; ++i) {
      const int nt = wave * 7 + i;
      if (nt < 54) {
        const int n = nt * 16 + m;
        const float bs = om_b[n];
        const int g = n / 27;
        const int j = n - 27 * g;
        const int cj = j >> 3, jl = j & 7;
#pragma unroll
        for (int mt2 = 0; mt2 < 2; ++mt2)
#pragma unroll
          for (int r = 0; r < 4; ++r) {
            const int p = mt2 * 16 + kq * 4 + r;
            s_om[p * 1024 + (((g * 4 + cj + p) & 127) * 8) + jl] =
                (bf16_t)(acc[mt2][i][r] + bs);
          }
      }
    }
  }
  __syncthreads();

  // ---- sampling: 32 px x 32 g = 1024 tasks, 2/thread
  const int gl = lane >> 4;
  const int g = wave * 4 + gl;
#pragma unroll
  for (int iter = 0; iter < 2; ++iter) {
    const int p = (lane & 15) + iter * 16;
    const int pix = pix0 + p;
    const int xw = pix & 63;
    const int y = (pix >> 6) & 63;
    const int img = pix >> 12;
    const bf16_t* plane = value_g + ((size_t)(img * G + g) << 15);

    // read 27 om values: 4 rotated 16B chunks, direct logical mapping
    const bf16_t* omp = &s_om[p * 1024];
    const int g4p = g * 4 + p;
    const bf16x8 o0 = *(const bf16x8*)(omp + ((g4p + 0) & 127) * 8);
    const bf16x8 o1 = *(const bf16x8*)(omp + ((g4p + 1) & 127) * 8);
    const bf16x8 o2 = *(const bf16x8*)(omp + ((g4p + 2) & 127) * 8);
    const bf16x8 o3 = *(const bf16x8*)(omp + ((g4p + 3) & 127) * 8);
    float arr[27];
#pragma unroll
    for (int j = 0; j < 8; ++j) {
      arr[j] = (float)o0[j];
      arr[8 + j] = (float)o1[j];
      arr[16 + j] = (float)o2[j];
    }
#pragma unroll
    for (int j = 0; j < 3; ++j) arr[24 + j] = (float)o3[j];

    float acc[GC];
#pragma unroll
    for (int c = 0; c < GC; ++c) acc[c] = 0.0f;

#pragma unroll
    for (int k = 0; k < 9; ++k) {
      const float px = (float)(xw + (k % 3) - 1) + arr[2 * k];
      const float py = (float)(y + (k / 3) - 1) + arr[2 * k + 1];
      const float mk = arr[18 + k];
      const float x0f = floorf(px), y0f = floorf(py);
      const float tx = px - x0f, ty = py - y0f;
      const int ix = (int)x0f, iy = (int)y0f;

      const float vx0 = (ix >= 0 && ix < WW) ? 1.0f : 0.0f;
      const float vx1 = (ix + 1 >= 0 && ix + 1 < WW) ? 1.0f : 0.0f;
      const float vy0 = (iy >= 0 && iy < HH) ? 1.0f : 0.0f;
      const float vy1 = (iy + 1 >= 0 && iy + 1 < HH) ? 1.0f : 0.0f;
      const int ix0 = min(max(ix, 0), WW - 1);
      const int ix1 = min(max(ix + 1, 0), WW - 1);
      const int iy0 = min(max(iy, 0), HH - 1);
      const int iy1 = min(max(iy + 1, 0), HH - 1);

      const bf16x8 v00 = *(const bf16x8*)(plane + (size_t)(iy0 * WW + ix0) * GC);
      const bf16x8 v01 = *(const bf16x8*)(plane + (size_t)(iy0 * WW + ix1) * GC);
      const bf16x8 v10 = *(const bf16x8*)(plane + (size_t)(iy1 * WW + ix0) * GC);
      const bf16x8 v11 = *(const bf16x8*)(plane + (size_t)(iy1 * WW + ix1) * GC);

      const float w00 = mk * (1.0f - ty) * (1.0f - tx) * vy0 * vx0;
      const float w01 = mk * (1.0f - ty) * tx * vy0 * vx1;
      const float w10 = mk * ty * (1.0f - tx) * vy1 * vx0;
      const float w11 = mk * ty * tx * vy1 * vx1;

#pragma unroll
      for (int c = 0; c < GC; ++c) {
        float s = acc[c];
        s = fmaf(w00, (float)v00[c], s);
        s = fmaf(w01, (float)v01[c], s);
        s = fmaf(w10, (float)v10[c], s);
        s = fmaf(w11, (float)v11[c], s);
        acc[c] = s;
      }
    }

    bf16x8 sv;
#pragma unroll
    for (int c = 0; c < GC; ++c) sv[c] = (bf16_t)acc[c];
    *(bf16x8*)(sampledF + (size_t)(blockIdx.x * 2 + iter) * 4096 + wave * 512 +
               lane * 8) = sv;
  }
}

// ---------------- K4: out = sampledF @ op_wF, M=64/block, fp32 NHWC ----------
__global__ __launch_bounds__(512, 4) void out_gemm_kernel(
    const bf16_t* __restrict__ AF, const bf16_t* __restrict__ BF,
    float* __restrict__ out) {
  const int lane = threadIdx.x & 63;
  const int wave = threadIdx.x >> 6;
  const int mq = wave >> 1;
  const int nh = wave & 1;
  const int mt = blockIdx.x * 4 + mq;
  const int m = lane & 15;
  const int kq = lane >> 4;

  const bf16_t* Ap = AF + (size_t)mt * 4096 + lane * 8;
  const bf16_t* Bp = BF + (size_t)(nh * 8) * 4096 + lane * 8;

  f32x4 acc[8] = {};
#pragma unroll
  for (int ks = 0; ks < 8; ++ks) {
    const bf16x8 a = *(const bf16x8*)(Ap + ks * 512);
#pragma unroll
    for (int i = 0; i < 8; ++i) {
      const bf16x8 b = *(const bf16x8*)(Bp + (size_t)i * 4096 + ks * 512);
      acc[i] = __builtin_amdgcn_mfma_f32_16x16x32_bf16(a, b, acc[i], 0, 0, 0);
    }
  }

#pragma unroll
  for (int i = 0; i < 8; ++i) {
    const int n = (nh * 8 + i) * 16 + m;
#pragma unroll
    for (int r = 0; r < 4; ++r) {
      const int pix = mt * 16 + kq * 4 + r;
      out[(size_t)pix * CC + n] = acc[i][r];
    }
  }
}

extern "C" void kernel_launch(void* const* d_in, const int* in_sizes, int n_in,
                              void* d_out, int out_size, void* d_ws, size_t ws_size,
                              hipStream_t stream) {
  const float* x = (const float*)d_in[0];
  const float* dw_w = (const float*)d_in[1];
  const float* dw_b = (const float*)d_in[2];
  const float* om_w = (const float*)d_in[3];
  const float* om_b = (const float*)d_in[4];
  const float* vp_w = (const float*)d_in[5];
  const float* vp_b = (const float*)d_in[6];
  const float* op_w = (const float*)d_in[7];
  float* out = (float*)d_out;

  // workspace layout (bytes)
  char* ws = (char*)d_ws;
  bf16_t* value_g = (bf16_t*)ws;                      // 16,777,216
  bf16_t* xdwF = (bf16_t*)(ws + 16777216);            // 16,777,216
  bf16_t* sampledF = (bf16_t*)(ws + 33554432);        // 16,777,216
  bf16_t* om_wF = (bf16_t*)(ws + 50331648);           // 458,752
  bf16_t* vp_wF = (bf16_t*)(ws + 50790400);           // 131,072
  bf16_t* op_wF = (bf16_t*)(ws + 50921472);           // 131,072

  convert_weights_kernel<<<88, 256, 0, stream>>>(om_w, vp_w, op_w,
                                                 om_wF, vp_wF, op_wF);
  dwconv_value_kernel<<<NN * HH, 512, 0, stream>>>(x, dw_w, dw_b, vp_wF, vp_b,
                                                   xdwF, value_g);
  om_sample_mfma_kernel<<<NPIX / 32, 512, 0, stream>>>(xdwF, om_wF, om_b,
                                                       value_g, sampledF);
  out_gemm_kernel<<<NPIX / 64, 512, 0, stream>>>(sampledF, op_wF, out);
}